// Round 9
// baseline (562.701 us; speedup 1.0000x reference)
//
#include <hip/hip_runtime.h>
#include <hip/hip_bf16.h>

#define NB 16
#define NC 256
#define NS 4096
#define NL 256
#define NE 256
#define NHH 4
#define HDD 64

using bf16 = __hip_bfloat16;
typedef short bf16x8 __attribute__((ext_vector_type(8)));
typedef float f32x4 __attribute__((ext_vector_type(4)));

__device__ __forceinline__ float bf16r(float x) {
    return __bfloat162float(__float2bfloat16(x));
}
__device__ __forceinline__ float rsqrt_nr(float x) {
    float r = rsqrtf(x);
    r = r * (1.5f - 0.5f * x * r * r);
    return r;
}
__device__ __forceinline__ ushort us(float x) {
    bf16 h = __float2bfloat16(x);
    return *(ushort*)&h;
}

// ---------------- K0: transpose weights to bf16 [out][in] so MFMA B/A frags
// (contiguous along k) load straight from global.
__global__ void __launch_bounds__(256) wt_kernel(const float* __restrict__ Wq,
                                                 const float* __restrict__ Wk,
                                                 const float* __restrict__ Wv,
                                                 const float* __restrict__ Wo,
                                                 ushort* __restrict__ wqt,
                                                 ushort* __restrict__ wkt,
                                                 ushort* __restrict__ wvt,
                                                 ushort* __restrict__ wot) {
    int m = blockIdx.x >> 3, strip = blockIdx.x & 7;
    const float* W = (m == 0) ? Wq : (m == 1) ? Wk : (m == 2) ? Wv : Wo;
    ushort* Wt = (m == 0) ? wqt : (m == 1) ? wkt : (m == 2) ? wvt : wot;
    int t = threadIdx.x;
    __shared__ float tile[32 * 257];
    int in0 = strip * 32;
    for (int i = 0; i < 32; i++) tile[i * 257 + t] = W[(size_t)(in0 + i) * 256 + t];
    __syncthreads();
    ushort vals[32];
#pragma unroll
    for (int i = 0; i < 32; i++) vals[i] = us(tile[i * 257 + t]);
#pragma unroll
    for (int i = 0; i < 32; i += 8)
        *(uint4*)(Wt + (size_t)t * 256 + in0 + i) = *(const uint4*)(vals + i);
}

// ---------------- K1: AdaLN modulation: mod = silu(ref_embeds) @ W_ada + b_ada
__global__ void __launch_bounds__(256) mod_kernel(const float* __restrict__ ref_embeds,
                                                  const float* __restrict__ W_ada,
                                                  const float* __restrict__ b_ada,
                                                  float* __restrict__ mod) {
    int b = blockIdx.x / 12, jc = blockIdx.x % 12;
    int t = threadIdx.x;
    __shared__ float silu[NC];
    __shared__ float part[256];
    float x = ref_embeds[b * NC + t];
    silu[t] = x / (1.f + expf(-x));
    __syncthreads();
    int j = jc * 64 + (t & 63);
    int cq = t >> 6;
    float acc = 0.f;
#pragma unroll 8
    for (int c = cq * 64; c < cq * 64 + 64; c++) acc += silu[c] * W_ada[c * 3 * NC + j];
    part[t] = acc;
    __syncthreads();
    if (t < 64) {
        mod[b * 3 * NC + j] = part[t] + part[t + 64] + part[t + 128] + part[t + 192] + b_ada[j];
    }
}

// ---------------- K2: LN(refs) -> K,V projections via MFMA. Block = 64 text rows.
__global__ void __launch_bounds__(256) kv_kernel(const float* __restrict__ refs,
                                                 const float* __restrict__ lw,
                                                 const float* __restrict__ lb,
                                                 const ushort* __restrict__ Wkt,
                                                 const float* __restrict__ bk,
                                                 const ushort* __restrict__ Wvt,
                                                 const float* __restrict__ bv,
                                                 bf16* __restrict__ kbuf,
                                                 bf16* __restrict__ vbuf) {
    int blk = blockIdx.x;  // b*4 + lgroup
    int b = blk >> 2;
    int l0 = (blk & 3) << 6;
    int t = threadIdx.x;
    __shared__ ushort At[64 * 264];
    __shared__ float lws[NC], lbs[NC];
    lws[t] = lw[t];
    lbs[t] = lb[t];
    int r = t >> 2, j = t & 3;
    const float* rp = refs + ((size_t)(b * NL + l0 + r)) * NC + j * 64;
    float v[64];
#pragma unroll
    for (int i = 0; i < 16; i++) {
        float4 f = *(const float4*)(rp + i * 4);
        v[i * 4 + 0] = f.x; v[i * 4 + 1] = f.y; v[i * 4 + 2] = f.z; v[i * 4 + 3] = f.w;
    }
    float s = 0;
#pragma unroll
    for (int i = 0; i < 64; i++) s += v[i];
    s += __shfl_xor(s, 1, 64);
    s += __shfl_xor(s, 2, 64);
    float mu = s * (1.f / NC);
    float vr = 0;
#pragma unroll
    for (int i = 0; i < 64; i++) {
        float d = v[i] - mu;
        vr += d * d;
    }
    vr += __shfl_xor(vr, 1, 64);
    vr += __shfl_xor(vr, 2, 64);
    float rs = rsqrt_nr(vr * (1.f / NC) + 1e-5f);
    __syncthreads();  // lws/lbs ready
    ushort nv[64];
#pragma unroll
    for (int i = 0; i < 64; i++) {
        int c = j * 64 + i;
        nv[i] = us((v[i] - mu) * rs * lws[c] + lbs[c]);
    }
#pragma unroll
    for (int i = 0; i < 64; i += 4)
        *(uint2*)(At + r * 264 + j * 64 + i) = *(const uint2*)(nv + i);
    __syncthreads();

    int w = t >> 6, lane = t & 63, l16 = lane & 15, quad = lane >> 4;
    int r0 = w * 16;
    f32x4 zero = {0.f, 0.f, 0.f, 0.f};
    f32x4 ak[16], av[16];
#pragma unroll
    for (int et = 0; et < 16; et++) { ak[et] = zero; av[et] = zero; }
    const ushort* ap = At + (r0 + l16) * 264 + quad * 8;
    const ushort* kp = Wkt + (size_t)l16 * NC + quad * 8;
    const ushort* vp = Wvt + (size_t)l16 * NC + quad * 8;
#pragma unroll
    for (int kc = 0; kc < 8; kc++) {
        bf16x8 a = *(const bf16x8*)(ap + kc * 32);
#pragma unroll
        for (int et = 0; et < 16; et++) {
            bf16x8 bbk = *(const bf16x8*)(kp + (size_t)et * 16 * NC + kc * 32);
            ak[et] = __builtin_amdgcn_mfma_f32_16x16x32_bf16(a, bbk, ak[et], 0, 0, 0);
        }
#pragma unroll
        for (int et = 0; et < 16; et++) {
            bf16x8 bbv = *(const bf16x8*)(vp + (size_t)et * 16 * NC + kc * 32);
            av[et] = __builtin_amdgcn_mfma_f32_16x16x32_bf16(a, bbv, av[et], 0, 0, 0);
        }
    }
#pragma unroll
    for (int et = 0; et < 16; et++) {
        int e = et * 16 + l16;
        float bkv = bk[e], bvv = bv[e];
#pragma unroll
        for (int rr = 0; rr < 4; rr++) {
            size_t row = (size_t)(b * NL + l0 + r0 + quad * 4 + rr);
            kbuf[row * NE + e] = __float2bfloat16(ak[et][rr] + bkv);
            vbuf[row * NE + e] = __float2bfloat16(av[et][rr] + bvv);
        }
    }
}

// ---------------- K2b: transpose V per head: vbuf [B,L,E] -> vtbuf [B,H,HD,L]
__global__ void __launch_bounds__(256) vt_kernel(const bf16* __restrict__ vbuf,
                                                 ushort* __restrict__ vtbuf) {
    int bh = blockIdx.x;
    int b = bh >> 2, h = bh & 3;
    int t = threadIdx.x;
    __shared__ ushort tile[64 * 264];
    const ushort* vp = (const ushort*)vbuf + ((size_t)b * NL) * NE + h * HDD;
#pragma unroll
    for (int i = 0; i < 8; i++) {
        int l = i * 32 + (t >> 3);
        uint4 v = *(const uint4*)(vp + (size_t)l * NE + (t & 7) * 8);
        const ushort* v8 = (const ushort*)&v;
#pragma unroll
        for (int j = 0; j < 8; j++) tile[((t & 7) * 8 + j) * 264 + l] = v8[j];
    }
    __syncthreads();
    ushort* op = vtbuf + (size_t)bh * HDD * NL;
#pragma unroll
    for (int i = 0; i < 8; i++) {
        int d = i * 8 + (t >> 5);
        int l = (t & 31) * 8;
        *(uint4*)(op + (size_t)d * NL + l) = *(const uint4*)(tile + d * 264 + l);
    }
}

// ---------------- K3a: transpose + LN: img_x [B,C,S] fp32 -> xq [B,S,C] bf16.
__global__ void __launch_bounds__(256) xln_kernel(const float* __restrict__ img_x,
                                                  const float* __restrict__ lw,
                                                  const float* __restrict__ lb,
                                                  ushort* __restrict__ xq) {
    int blk = blockIdx.x;  // b*16 + schunk
    int b = blk >> 4;
    int sb = (blk & 15) << 8;
    int t = threadIdx.x;
    int l63 = t & 63, wq = t >> 6;
    __shared__ float part_s[4][256], part_q[4][256];
    __shared__ float mu_s[256], rs_s[256];
    __shared__ ushort tile[256 * 66];
    __shared__ float lws[NC], lbs[NC];
    lws[t] = lw[t];
    lbs[t] = lb[t];

    const float* xb = img_x + (size_t)b * NC * NS + sb;
    float s0 = 0.f, s1 = 0.f, s2 = 0.f, s3 = 0.f;
    float q0 = 0.f, q1 = 0.f, q2 = 0.f, q3 = 0.f;
    for (int it = 0; it < 64; it++) {
        int c = it * 4 + wq;
        float4 v = *(const float4*)(xb + (size_t)c * NS + l63 * 4);
        s0 += v.x; q0 += v.x * v.x;
        s1 += v.y; q1 += v.y * v.y;
        s2 += v.z; q2 += v.z * v.z;
        s3 += v.w; q3 += v.w * v.w;
    }
    part_s[wq][l63 * 4 + 0] = s0; part_q[wq][l63 * 4 + 0] = q0;
    part_s[wq][l63 * 4 + 1] = s1; part_q[wq][l63 * 4 + 1] = q1;
    part_s[wq][l63 * 4 + 2] = s2; part_q[wq][l63 * 4 + 2] = q2;
    part_s[wq][l63 * 4 + 3] = s3; part_q[wq][l63 * 4 + 3] = q3;
    __syncthreads();
    {
        float sm = part_s[0][t] + part_s[1][t] + part_s[2][t] + part_s[3][t];
        float sq = part_q[0][t] + part_q[1][t] + part_q[2][t] + part_q[3][t];
        float mu = sm * (1.f / NC);
        mu_s[t] = mu;
        rs_s[t] = rsqrt_nr(sq * (1.f / NC) - mu * mu + 1e-5f);
    }
    __syncthreads();
    float4 mu4 = *(const float4*)&mu_s[l63 * 4];
    float4 rs4 = *(const float4*)&rs_s[l63 * 4];
    for (int ch = 0; ch < 4; ch++) {
#pragma unroll
        for (int it2 = 0; it2 < 16; it2++) {
            int cl = it2 * 4 + wq;
            int c = ch * 64 + cl;
            float4 v = *(const float4*)(xb + (size_t)c * NS + l63 * 4);
            float wv = lws[c], bb = lbs[c];
            tile[(l63 * 4 + 0) * 66 + cl] = us((v.x - mu4.x) * rs4.x * wv + bb);
            tile[(l63 * 4 + 1) * 66 + cl] = us((v.y - mu4.y) * rs4.y * wv + bb);
            tile[(l63 * 4 + 2) * 66 + cl] = us((v.z - mu4.z) * rs4.z * wv + bb);
            tile[(l63 * 4 + 3) * 66 + cl] = us((v.w - mu4.w) * rs4.w * wv + bb);
        }
        __syncthreads();
        ushort* xrow = xq + ((size_t)(b * NS + sb)) * NC + ch * 64 + (t & 7) * 8;
#pragma unroll
        for (int i = 0; i < 8; i++) {
            int s = i * 32 + (t >> 3);
            const ushort* tp = tile + s * 66 + (t & 7) * 8;
            uint u0 = *(const uint*)(tp);
            uint u1 = *(const uint*)(tp + 2);
            uint u2 = *(const uint*)(tp + 4);
            uint u3 = *(const uint*)(tp + 6);
            uint4 uu = {u0, u1, u2, u3};
            *(uint4*)(xrow + (size_t)s * NC) = uu;
        }
        __syncthreads();
    }
}

// ---------------- K3b: Q GEMM: qbuf = xq @ Wqt^T + bq (unchanged from R8).
__global__ void __launch_bounds__(256, 2) qmm_kernel(const ushort* __restrict__ xq,
                                                     const ushort* __restrict__ Wqt,
                                                     const float* __restrict__ bq,
                                                     bf16* __restrict__ qbuf) {
    int blk = blockIdx.x;  // b*64 + rc*2 + eh
    int b = blk >> 6;
    int rc = (blk >> 1) & 31;
    int eh = blk & 1;
    int t = threadIdx.x;
    int w = t >> 6, lane = t & 63, l16 = lane & 15, quad = lane >> 4;
    int r0 = rc * 128 + w * 32;
    int e0 = eh * 128;

    __shared__ __attribute__((aligned(16))) char sB[65536];

    const char* ab = (const char*)xq + ((size_t)(b * NS + r0 + l16)) * 512 + quad * 16;
    bf16x8 a[2][8];
#pragma unroll
    for (int rt = 0; rt < 2; rt++)
#pragma unroll
        for (int kc = 0; kc < 8; kc++)
            a[rt][kc] = *(const bf16x8*)(ab + (size_t)rt * 16 * 512 + kc * 64);

    const char* wsrc = (const char*)(Wqt + (size_t)e0 * NC);
#pragma unroll
    for (int ii = 0; ii < 2; ii++) {
        uint4 tmp[8];
#pragma unroll
        for (int j = 0; j < 8; j++) {
            int g = ((ii * 8 + j) * 256 + t) * 16;
            tmp[j] = *(const uint4*)(wsrc + g);
        }
#pragma unroll
        for (int j = 0; j < 8; j++) {
            int g = ((ii * 8 + j) * 256 + t) * 16;
            *(uint4*)(sB + (g ^ (((g >> 9) & 7) << 4))) = tmp[j];
        }
    }
    __syncthreads();

    f32x4 zero = {0.f, 0.f, 0.f, 0.f};
    f32x4 acc[2][8];
#pragma unroll
    for (int rt = 0; rt < 2; rt++)
#pragma unroll
        for (int et = 0; et < 8; et++) acc[rt][et] = zero;
    int swz = (l16 & 7) << 4;
#pragma unroll
    for (int kc = 0; kc < 8; kc++) {
        bf16x8 bB[8];
#pragma unroll
        for (int et = 0; et < 8; et++) {
            int e = et * 16 + l16;
            bB[et] = *(const bf16x8*)(sB + e * 512 + ((quad * 16 + kc * 64) ^ swz));
        }
#pragma unroll
        for (int et = 0; et < 8; et++) {
#pragma unroll
            for (int rt = 0; rt < 2; rt++)
                acc[rt][et] = __builtin_amdgcn_mfma_f32_16x16x32_bf16(a[rt][kc], bB[et], acc[rt][et], 0, 0, 0);
        }
    }
#pragma unroll
    for (int et = 0; et < 8; et++) {
        int e = e0 + et * 16 + l16;
        float bqv = bq[e];
#pragma unroll
        for (int rt = 0; rt < 2; rt++) {
#pragma unroll
            for (int rr = 0; rr < 4; rr++) {
                int s = r0 + rt * 16 + quad * 4 + rr;
                qbuf[((size_t)(b * NS + s)) * NE + e] = __float2bfloat16(acc[rt][et][rr] + bqv);
            }
        }
    }
}

// ---------------- K4: MFMA attention v4.
// 512-thread blocks (8 waves), launch_bounds(512,4) -> VGPR<=128, 2 blocks/CU,
// 4 waves/SIMD (2x TLP vs v3). Same 64KB swizzled sK/sV shared by 8 waves.
// Softmax chain shortened: __expf (hw exp), no bf16r, P packed UNNORMALIZED
// right after exp (sum-reduce off critical path); 1/sum applied post-PV via
// 4 shfl + 16 muls. Wloc[] eliminated (VGPR down from 208).
__global__ void __launch_bounds__(512, 4) attn_kernel(const bf16* __restrict__ qbuf,
                                                      const bf16* __restrict__ kbuf,
                                                      const ushort* __restrict__ vtbuf,
                                                      const int* __restrict__ masks,
                                                      bf16* __restrict__ obuf) {
    int blk = blockIdx.x;          // bh*8 + chunk
    int chunk = blk & 7;
    int bh = blk >> 3;
    int h = bh & 3;
    int b = bh >> 2;
    int t = threadIdx.x;
    int w = t >> 6, lane = t & 63;  // w in 0..7
    int l16 = lane & 15, quad = lane >> 4;

    __shared__ __attribute__((aligned(16))) char sK[32768];  // [k=256][d-bytes=128] swz
    __shared__ __attribute__((aligned(16))) char sV[32768];  // [d=64][l-bytes=512] swz

    // ---- stage K and V^T (512 threads x 16B x 4 iters = 32KB each)
    const char* kgb = (const char*)kbuf + ((size_t)(b * NL) * NE + h * HDD) * 2;
    const char* vgb = (const char*)vtbuf + (size_t)bh * HDD * NL * 2;
#pragma unroll
    for (int i = 0; i < 4; i++) {
        int g = t * 16 + i * 8192;
        uint4 kv = *(const uint4*)(kgb + (size_t)(g >> 7) * 512 + (g & 127));
        *(uint4*)(sK + (g ^ (((g >> 7) & 7) << 4))) = kv;
        uint4 vv = *(const uint4*)(vgb + g);
        *(uint4*)(sV + (g ^ (((g >> 9) & 7) << 4))) = vv;
    }

    // ---- masks -> wave ballots -> per-lane nibble words (bit kt*4+r)
    const int* mp = masks + b * NL;
    unsigned long long bal0 = __ballot(mp[lane] != 0);
    unsigned long long bal1 = __ballot(mp[64 + lane] != 0);
    unsigned long long bal2 = __ballot(mp[128 + lane] != 0);
    unsigned long long bal3 = __ballot(mp[192 + lane] != 0);
    uint mw0 = 0, mw1 = 0;
#pragma unroll
    for (int kk = 0; kk < 4; kk++) {
        mw0 |= (uint)((bal0 >> (16 * kk + 4 * quad)) & 15ULL) << (4 * kk);
        mw0 |= (uint)((bal1 >> (16 * kk + 4 * quad)) & 15ULL) << (4 * kk + 16);
        mw1 |= (uint)((bal2 >> (16 * kk + 4 * quad)) & 15ULL) << (4 * kk);
        mw1 |= (uint)((bal3 >> (16 * kk + 4 * quad)) & 15ULL) << (4 * kk + 16);
    }

    __syncthreads();

    int sbase = chunk * 512;
    int kswz = (l16 & 7) << 4;
    int src0 = l16 + 32 * (quad & 1);
    int src1 = src0 + 16;
    bool ahi = quad >= 2;

    for (int it = 0; it < 4; it++) {
        int s0 = sbase + it * 128;
        const ushort* qp = (const ushort*)qbuf +
                           ((size_t)(b * NS + s0 + w * 16 + l16)) * NE + h * HDD + quad * 8;
        bf16x8 af0 = *(const bf16x8*)qp;
        bf16x8 af1 = *(const bf16x8*)(qp + 32);

        // ---- QK^T (S^T): acc[kt][r] = S[q=l16][k=kt*16+quad*4+r]
        f32x4 acc[16];
#pragma unroll
        for (int kt = 0; kt < 16; kt++) {
            int row = kt * 16 + l16;
            bf16x8 kf0 = *(const bf16x8*)(sK + ((row * 128 + quad * 16) ^ kswz));
            bf16x8 kf1 = *(const bf16x8*)(sK + ((row * 128 + quad * 16 + 64) ^ kswz));
            f32x4 z = {0.f, 0.f, 0.f, 0.f};
            z = __builtin_amdgcn_mfma_f32_16x16x32_bf16(kf0, af0, z, 0, 0, 0);
            acc[kt] = __builtin_amdgcn_mfma_f32_16x16x32_bf16(kf1, af1, z, 0, 0, 0);
        }

        // ---- exp (hw) + mask + pack UNNORMALIZED bf16 pairs; sum alongside.
        // pk[2kt+hf] covers k = 16kt + 4quad + 2hf + {0,1}
        float srow = 0.f;
        uint pk[32];
#pragma unroll
        for (int kt = 0; kt < 16; kt++) {
            uint nib = ((kt < 8) ? mw0 : mw1) >> (4 * (kt & 7));
            float p0 = __expf(acc[kt][0] * 0.125f);
            float p1 = __expf(acc[kt][1] * 0.125f);
            float p2 = __expf(acc[kt][2] * 0.125f);
            float p3 = __expf(acc[kt][3] * 0.125f);
            p0 = (nib & 1) ? 0.f : p0;
            p1 = (nib & 2) ? 0.f : p1;
            p2 = (nib & 4) ? 0.f : p2;
            p3 = (nib & 8) ? 0.f : p3;
            srow += (p0 + p1) + (p2 + p3);
            pk[2 * kt] = (uint)us(p0) | ((uint)us(p1) << 16);
            pk[2 * kt + 1] = (uint)us(p2) | ((uint)us(p3) << 16);
        }
        srow += __shfl_xor(srow, 16, 64);
        srow += __shfl_xor(srow, 32, 64);
        float inv = 1.f / srow;
        // fetch inv for this lane's OUTPUT rows (q = quad*4+r) early
        float invr[4];
#pragma unroll
        for (int r = 0; r < 4; r++) invr[r] = __shfl(inv, quad * 4 + r, 64);

        // ---- PV with in-register P exchange (A-frag: lane needs k=32kc+8quad+j)
        f32x4 oacc[4];
#pragma unroll
        for (int dt = 0; dt < 4; dt++) oacc[dt] = f32x4{0.f, 0.f, 0.f, 0.f};
#pragma unroll
        for (int kc = 0; kc < 8; kc++) {
            uint a0 = (uint)__shfl((int)pk[4 * kc + 0], src0, 64);
            uint b0 = (uint)__shfl((int)pk[4 * kc + 2], src0, 64);
            uint a1 = (uint)__shfl((int)pk[4 * kc + 1], src0, 64);
            uint b1 = (uint)__shfl((int)pk[4 * kc + 3], src0, 64);
            uint a2 = (uint)__shfl((int)pk[4 * kc + 0], src1, 64);
            uint b2 = (uint)__shfl((int)pk[4 * kc + 2], src1, 64);
            uint a3 = (uint)__shfl((int)pk[4 * kc + 1], src1, 64);
            uint b3 = (uint)__shfl((int)pk[4 * kc + 3], src1, 64);
            union { uint u[4]; bf16x8 v; } pu;
            pu.u[0] = ahi ? b0 : a0;
            pu.u[1] = ahi ? b1 : a1;
            pu.u[2] = ahi ? b2 : a2;
            pu.u[3] = ahi ? b3 : a3;
#pragma unroll
            for (int dt = 0; dt < 4; dt++) {
                int row = dt * 16 + l16;
                bf16x8 vb = *(const bf16x8*)(sV + ((row * 512 + kc * 64 + quad * 16) ^ kswz));
                oacc[dt] = __builtin_amdgcn_mfma_f32_16x16x32_bf16(pu.v, vb, oacc[dt], 0, 0, 0);
            }
        }

        // ---- normalize post-PV (rows q=quad*4+r) and store
        bf16* op = obuf + ((size_t)(b * NS + s0 + w * 16 + quad * 4)) * NE + h * HDD + l16;
#pragma unroll
        for (int dt = 0; dt < 4; dt++) {
#pragma unroll
            for (int r = 0; r < 4; r++)
                op[(size_t)r * NE + dt * 16] = __float2bfloat16(oacc[dt][r] * invr[r]);
        }
    }
}

// ---------------- K5: Y^T = Wo^T . o^T via MFMA -> AdaLN -> +x -> out [B,C,S].
__global__ void __launch_bounds__(256) out_kernel(const bf16* __restrict__ obuf,
                                                  const ushort* __restrict__ Wot,
                                                  const float* __restrict__ bo,
                                                  const float* __restrict__ mod,
                                                  const float* __restrict__ img_x,
                                                  float* __restrict__ out) {
    int blk = blockIdx.x;  // b * 64 + s-tile
    int b = blk >> 6;
    int s0 = (blk & 63) << 6;
    int t = threadIdx.x;
    int w = t >> 6, lane = t & 63, l16 = lane & 15, quad = lane >> 4;
    int c0 = w * 64;

    f32x4 zero = {0.f, 0.f, 0.f, 0.f};
    f32x4 acc[4][4];
#pragma unroll
    for (int ct = 0; ct < 4; ct++)
#pragma unroll
        for (int st = 0; st < 4; st++) acc[ct][st] = zero;

    const ushort* ap0 = Wot + (size_t)(c0 + l16) * NE + quad * 8;
    const ushort* bp0 = (const ushort*)obuf + ((size_t)(b * NS + s0 + l16)) * NE + quad * 8;
#pragma unroll
    for (int kc = 0; kc < 8; kc++) {
        bf16x8 a[4], bb[4];
#pragma unroll
        for (int ct = 0; ct < 4; ct++)
            a[ct] = *(const bf16x8*)(ap0 + (size_t)ct * 16 * NE + kc * 32);
#pragma unroll
        for (int st = 0; st < 4; st++)
            bb[st] = *(const bf16x8*)(bp0 + (size_t)st * 16 * NE + kc * 32);
#pragma unroll
        for (int ct = 0; ct < 4; ct++)
#pragma unroll
            for (int st = 0; st < 4; st++)
                acc[ct][st] = __builtin_amdgcn_mfma_f32_16x16x32_bf16(a[ct], bb[st], acc[ct][st], 0, 0, 0);
    }

#pragma unroll
    for (int ct = 0; ct < 4; ct++) {
#pragma unroll
        for (int r = 0; r < 4; r++) {
            int c = c0 + ct * 16 + quad * 4 + r;
            float sh = mod[b * 768 + c];
            float scv = mod[b * 768 + 256 + c];
            float ga = mod[b * 768 + 512 + c];
            float bov = bo[c];
            const float* xr = img_x + ((size_t)(b * NC + c)) * NS + s0;
            float* orow = out + ((size_t)(b * NC + c)) * NS + s0;
#pragma unroll
            for (int st = 0; st < 4; st++) {
                float y = ga * ((acc[ct][st][r] + bov) * (1.f + scv) + sh) + xr[st * 16 + l16];
                orow[st * 16 + l16] = y;
            }
        }
    }
}

extern "C" void kernel_launch(void* const* d_in, const int* in_sizes, int n_in,
                              void* d_out, int out_size, void* d_ws, size_t ws_size,
                              hipStream_t stream) {
    const float* img_x = (const float*)d_in[0];
    const float* refs = (const float*)d_in[1];
    const int* masks = (const int*)d_in[2];
    const float* ref_embeds = (const float*)d_in[3];
    const float* ln_img_w = (const float*)d_in[4];
    const float* ln_img_b = (const float*)d_in[5];
    const float* ln_txt_w = (const float*)d_in[6];
    const float* ln_txt_b = (const float*)d_in[7];
    const float* Wq = (const float*)d_in[8];
    const float* bq = (const float*)d_in[9];
    const float* Wk = (const float*)d_in[10];
    const float* bk = (const float*)d_in[11];
    const float* Wv = (const float*)d_in[12];
    const float* bv = (const float*)d_in[13];
    const float* Wo = (const float*)d_in[14];
    const float* bo = (const float*)d_in[15];
    const float* W_ada = (const float*)d_in[16];
    const float* b_ada = (const float*)d_in[17];
    float* out = (float*)d_out;

    char* ws = (char*)d_ws;
    float* mod = (float*)ws;                               // 49152 B
    ushort* wqt = (ushort*)(ws + 49152);                   // 128 KB
    ushort* wkt = (ushort*)(ws + 180224);                  // 128 KB
    ushort* wvt = (ushort*)(ws + 311296);                  // 128 KB
    ushort* wot = (ushort*)(ws + 442368);                  // 128 KB
    bf16* kbuf = (bf16*)(ws + 573440);                     // 2 MB
    ushort* vtbuf = (ushort*)(ws + 2670592);               // 2 MB
    bf16* qbuf = (bf16*)(ws + 4767744);                    // 33.5 MB
    bf16* obuf = (bf16*)(ws + 38322176);                   // 33.5 MB
    bf16* vbuf = obuf;     // alias: dead after vt_kernel
    ushort* xq = (ushort*)obuf;  // alias: written by xln (after vt), read by qmm,
                                 // dead once attn writes obuf

    hipLaunchKernelGGL(wt_kernel, dim3(32), dim3(256), 0, stream,
                       Wq, Wk, Wv, Wo, wqt, wkt, wvt, wot);
    hipLaunchKernelGGL(mod_kernel, dim3(NB * 12), dim3(256), 0, stream,
                       ref_embeds, W_ada, b_ada, mod);
    hipLaunchKernelGGL(kv_kernel, dim3(NB * 4), dim3(256), 0, stream,
                       refs, ln_txt_w, ln_txt_b, wkt, bk, wvt, bv, kbuf, vbuf);
    hipLaunchKernelGGL(vt_kernel, dim3(NB * NHH), dim3(256), 0, stream,
                       vbuf, vtbuf);
    hipLaunchKernelGGL(xln_kernel, dim3(NB * 16), dim3(256), 0, stream,
                       img_x, ln_img_w, ln_img_b, xq);
    hipLaunchKernelGGL(qmm_kernel, dim3(NB * 64), dim3(256), 0, stream,
                       xq, wqt, bq, qbuf);
    hipLaunchKernelGGL(attn_kernel, dim3(NB * NHH * 8), dim3(512), 0, stream,
                       qbuf, kbuf, vtbuf, masks, obuf);
    hipLaunchKernelGGL(out_kernel, dim3(NB * (NS / 64)), dim3(256), 0, stream,
                       obuf, wot, bo, mod, img_x, out);
}

// Round 10
// 379.634 us; speedup vs baseline: 1.4822x; 1.4822x over previous
//
#include <hip/hip_runtime.h>
#include <hip/hip_bf16.h>

#define NB 16
#define NC 256
#define NS 4096
#define NL 256
#define NE 256
#define NHH 4
#define HDD 64

using bf16 = __hip_bfloat16;
typedef short bf16x8 __attribute__((ext_vector_type(8)));
typedef float f32x4 __attribute__((ext_vector_type(4)));

__device__ __forceinline__ float bf16r(float x) {
    return __bfloat162float(__float2bfloat16(x));
}
__device__ __forceinline__ float rsqrt_nr(float x) {
    float r = rsqrtf(x);
    r = r * (1.5f - 0.5f * x * r * r);
    return r;
}
__device__ __forceinline__ ushort us(float x) {
    bf16 h = __float2bfloat16(x);
    return *(ushort*)&h;
}

// ---------------- K0: transpose weights to bf16 [out][in] so MFMA B/A frags
// (contiguous along k) load straight from global.
__global__ void __launch_bounds__(256) wt_kernel(const float* __restrict__ Wq,
                                                 const float* __restrict__ Wk,
                                                 const float* __restrict__ Wv,
                                                 const float* __restrict__ Wo,
                                                 ushort* __restrict__ wqt,
                                                 ushort* __restrict__ wkt,
                                                 ushort* __restrict__ wvt,
                                                 ushort* __restrict__ wot) {
    int m = blockIdx.x >> 3, strip = blockIdx.x & 7;
    const float* W = (m == 0) ? Wq : (m == 1) ? Wk : (m == 2) ? Wv : Wo;
    ushort* Wt = (m == 0) ? wqt : (m == 1) ? wkt : (m == 2) ? wvt : wot;
    int t = threadIdx.x;
    __shared__ float tile[32 * 257];
    int in0 = strip * 32;
    for (int i = 0; i < 32; i++) tile[i * 257 + t] = W[(size_t)(in0 + i) * 256 + t];
    __syncthreads();
    ushort vals[32];
#pragma unroll
    for (int i = 0; i < 32; i++) vals[i] = us(tile[i * 257 + t]);
#pragma unroll
    for (int i = 0; i < 32; i += 8)
        *(uint4*)(Wt + (size_t)t * 256 + in0 + i) = *(const uint4*)(vals + i);
}

// ---------------- K1: AdaLN modulation: mod = silu(ref_embeds) @ W_ada + b_ada
__global__ void __launch_bounds__(256) mod_kernel(const float* __restrict__ ref_embeds,
                                                  const float* __restrict__ W_ada,
                                                  const float* __restrict__ b_ada,
                                                  float* __restrict__ mod) {
    int b = blockIdx.x / 12, jc = blockIdx.x % 12;
    int t = threadIdx.x;
    __shared__ float silu[NC];
    __shared__ float part[256];
    float x = ref_embeds[b * NC + t];
    silu[t] = x / (1.f + expf(-x));
    __syncthreads();
    int j = jc * 64 + (t & 63);
    int cq = t >> 6;
    float acc = 0.f;
#pragma unroll 8
    for (int c = cq * 64; c < cq * 64 + 64; c++) acc += silu[c] * W_ada[c * 3 * NC + j];
    part[t] = acc;
    __syncthreads();
    if (t < 64) {
        mod[b * 3 * NC + j] = part[t] + part[t + 64] + part[t + 128] + part[t + 192] + b_ada[j];
    }
}

// ---------------- K2: LN(refs) -> K,V projections via MFMA. Block = 64 text rows.
__global__ void __launch_bounds__(256) kv_kernel(const float* __restrict__ refs,
                                                 const float* __restrict__ lw,
                                                 const float* __restrict__ lb,
                                                 const ushort* __restrict__ Wkt,
                                                 const float* __restrict__ bk,
                                                 const ushort* __restrict__ Wvt,
                                                 const float* __restrict__ bv,
                                                 bf16* __restrict__ kbuf,
                                                 bf16* __restrict__ vbuf) {
    int blk = blockIdx.x;  // b*4 + lgroup
    int b = blk >> 2;
    int l0 = (blk & 3) << 6;
    int t = threadIdx.x;
    __shared__ ushort At[64 * 264];
    __shared__ float lws[NC], lbs[NC];
    lws[t] = lw[t];
    lbs[t] = lb[t];
    int r = t >> 2, j = t & 3;
    const float* rp = refs + ((size_t)(b * NL + l0 + r)) * NC + j * 64;
    float v[64];
#pragma unroll
    for (int i = 0; i < 16; i++) {
        float4 f = *(const float4*)(rp + i * 4);
        v[i * 4 + 0] = f.x; v[i * 4 + 1] = f.y; v[i * 4 + 2] = f.z; v[i * 4 + 3] = f.w;
    }
    float s = 0;
#pragma unroll
    for (int i = 0; i < 64; i++) s += v[i];
    s += __shfl_xor(s, 1, 64);
    s += __shfl_xor(s, 2, 64);
    float mu = s * (1.f / NC);
    float vr = 0;
#pragma unroll
    for (int i = 0; i < 64; i++) {
        float d = v[i] - mu;
        vr += d * d;
    }
    vr += __shfl_xor(vr, 1, 64);
    vr += __shfl_xor(vr, 2, 64);
    float rs = rsqrt_nr(vr * (1.f / NC) + 1e-5f);
    __syncthreads();  // lws/lbs ready
    ushort nv[64];
#pragma unroll
    for (int i = 0; i < 64; i++) {
        int c = j * 64 + i;
        nv[i] = us((v[i] - mu) * rs * lws[c] + lbs[c]);
    }
#pragma unroll
    for (int i = 0; i < 64; i += 4)
        *(uint2*)(At + r * 264 + j * 64 + i) = *(const uint2*)(nv + i);
    __syncthreads();

    int w = t >> 6, lane = t & 63, l16 = lane & 15, quad = lane >> 4;
    int r0 = w * 16;
    f32x4 zero = {0.f, 0.f, 0.f, 0.f};
    f32x4 ak[16], av[16];
#pragma unroll
    for (int et = 0; et < 16; et++) { ak[et] = zero; av[et] = zero; }
    const ushort* ap = At + (r0 + l16) * 264 + quad * 8;
    const ushort* kp = Wkt + (size_t)l16 * NC + quad * 8;
    const ushort* vp = Wvt + (size_t)l16 * NC + quad * 8;
#pragma unroll
    for (int kc = 0; kc < 8; kc++) {
        bf16x8 a = *(const bf16x8*)(ap + kc * 32);
#pragma unroll
        for (int et = 0; et < 16; et++) {
            bf16x8 bbk = *(const bf16x8*)(kp + (size_t)et * 16 * NC + kc * 32);
            ak[et] = __builtin_amdgcn_mfma_f32_16x16x32_bf16(a, bbk, ak[et], 0, 0, 0);
        }
#pragma unroll
        for (int et = 0; et < 16; et++) {
            bf16x8 bbv = *(const bf16x8*)(vp + (size_t)et * 16 * NC + kc * 32);
            av[et] = __builtin_amdgcn_mfma_f32_16x16x32_bf16(a, bbv, av[et], 0, 0, 0);
        }
    }
#pragma unroll
    for (int et = 0; et < 16; et++) {
        int e = et * 16 + l16;
        float bkv = bk[e], bvv = bv[e];
#pragma unroll
        for (int rr = 0; rr < 4; rr++) {
            size_t row = (size_t)(b * NL + l0 + r0 + quad * 4 + rr);
            kbuf[row * NE + e] = __float2bfloat16(ak[et][rr] + bkv);
            vbuf[row * NE + e] = __float2bfloat16(av[et][rr] + bvv);
        }
    }
}

// ---------------- K2b: transpose V per head: vbuf [B,L,E] -> vtbuf [B,H,HD,L]
__global__ void __launch_bounds__(256) vt_kernel(const bf16* __restrict__ vbuf,
                                                 ushort* __restrict__ vtbuf) {
    int bh = blockIdx.x;
    int b = bh >> 2, h = bh & 3;
    int t = threadIdx.x;
    __shared__ ushort tile[64 * 264];
    const ushort* vp = (const ushort*)vbuf + ((size_t)b * NL) * NE + h * HDD;
#pragma unroll
    for (int i = 0; i < 8; i++) {
        int l = i * 32 + (t >> 3);
        uint4 v = *(const uint4*)(vp + (size_t)l * NE + (t & 7) * 8);
        const ushort* v8 = (const ushort*)&v;
#pragma unroll
        for (int j = 0; j < 8; j++) tile[((t & 7) * 8 + j) * 264 + l] = v8[j];
    }
    __syncthreads();
    ushort* op = vtbuf + (size_t)bh * HDD * NL;
#pragma unroll
    for (int i = 0; i < 8; i++) {
        int d = i * 8 + (t >> 5);
        int l = (t & 31) * 8;
        *(uint4*)(op + (size_t)d * NL + l) = *(const uint4*)(tile + d * 264 + l);
    }
}

// ---------------- K3a: transpose + LN: img_x [B,C,S] fp32 -> xq [B,S,C] bf16.
__global__ void __launch_bounds__(256) xln_kernel(const float* __restrict__ img_x,
                                                  const float* __restrict__ lw,
                                                  const float* __restrict__ lb,
                                                  ushort* __restrict__ xq) {
    int blk = blockIdx.x;  // b*16 + schunk
    int b = blk >> 4;
    int sb = (blk & 15) << 8;
    int t = threadIdx.x;
    int l63 = t & 63, wq = t >> 6;
    __shared__ float part_s[4][256], part_q[4][256];
    __shared__ float mu_s[256], rs_s[256];
    __shared__ ushort tile[256 * 66];
    __shared__ float lws[NC], lbs[NC];
    lws[t] = lw[t];
    lbs[t] = lb[t];

    const float* xb = img_x + (size_t)b * NC * NS + sb;
    float s0 = 0.f, s1 = 0.f, s2 = 0.f, s3 = 0.f;
    float q0 = 0.f, q1 = 0.f, q2 = 0.f, q3 = 0.f;
    for (int it = 0; it < 64; it++) {
        int c = it * 4 + wq;
        float4 v = *(const float4*)(xb + (size_t)c * NS + l63 * 4);
        s0 += v.x; q0 += v.x * v.x;
        s1 += v.y; q1 += v.y * v.y;
        s2 += v.z; q2 += v.z * v.z;
        s3 += v.w; q3 += v.w * v.w;
    }
    part_s[wq][l63 * 4 + 0] = s0; part_q[wq][l63 * 4 + 0] = q0;
    part_s[wq][l63 * 4 + 1] = s1; part_q[wq][l63 * 4 + 1] = q1;
    part_s[wq][l63 * 4 + 2] = s2; part_q[wq][l63 * 4 + 2] = q2;
    part_s[wq][l63 * 4 + 3] = s3; part_q[wq][l63 * 4 + 3] = q3;
    __syncthreads();
    {
        float sm = part_s[0][t] + part_s[1][t] + part_s[2][t] + part_s[3][t];
        float sq = part_q[0][t] + part_q[1][t] + part_q[2][t] + part_q[3][t];
        float mu = sm * (1.f / NC);
        mu_s[t] = mu;
        rs_s[t] = rsqrt_nr(sq * (1.f / NC) - mu * mu + 1e-5f);
    }
    __syncthreads();
    float4 mu4 = *(const float4*)&mu_s[l63 * 4];
    float4 rs4 = *(const float4*)&rs_s[l63 * 4];
    for (int ch = 0; ch < 4; ch++) {
#pragma unroll
        for (int it2 = 0; it2 < 16; it2++) {
            int cl = it2 * 4 + wq;
            int c = ch * 64 + cl;
            float4 v = *(const float4*)(xb + (size_t)c * NS + l63 * 4);
            float wv = lws[c], bb = lbs[c];
            tile[(l63 * 4 + 0) * 66 + cl] = us((v.x - mu4.x) * rs4.x * wv + bb);
            tile[(l63 * 4 + 1) * 66 + cl] = us((v.y - mu4.y) * rs4.y * wv + bb);
            tile[(l63 * 4 + 2) * 66 + cl] = us((v.z - mu4.z) * rs4.z * wv + bb);
            tile[(l63 * 4 + 3) * 66 + cl] = us((v.w - mu4.w) * rs4.w * wv + bb);
        }
        __syncthreads();
        ushort* xrow = xq + ((size_t)(b * NS + sb)) * NC + ch * 64 + (t & 7) * 8;
#pragma unroll
        for (int i = 0; i < 8; i++) {
            int s = i * 32 + (t >> 3);
            const ushort* tp = tile + s * 66 + (t & 7) * 8;
            uint u0 = *(const uint*)(tp);
            uint u1 = *(const uint*)(tp + 2);
            uint u2 = *(const uint*)(tp + 4);
            uint u3 = *(const uint*)(tp + 6);
            uint4 uu = {u0, u1, u2, u3};
            *(uint4*)(xrow + (size_t)s * NC) = uu;
        }
        __syncthreads();
    }
}

// ---------------- K3b: Q GEMM: qbuf = xq @ Wqt^T + bq (unchanged from R8).
__global__ void __launch_bounds__(256, 2) qmm_kernel(const ushort* __restrict__ xq,
                                                     const ushort* __restrict__ Wqt,
                                                     const float* __restrict__ bq,
                                                     bf16* __restrict__ qbuf) {
    int blk = blockIdx.x;  // b*64 + rc*2 + eh
    int b = blk >> 6;
    int rc = (blk >> 1) & 31;
    int eh = blk & 1;
    int t = threadIdx.x;
    int w = t >> 6, lane = t & 63, l16 = lane & 15, quad = lane >> 4;
    int r0 = rc * 128 + w * 32;
    int e0 = eh * 128;

    __shared__ __attribute__((aligned(16))) char sB[65536];

    const char* ab = (const char*)xq + ((size_t)(b * NS + r0 + l16)) * 512 + quad * 16;
    bf16x8 a[2][8];
#pragma unroll
    for (int rt = 0; rt < 2; rt++)
#pragma unroll
        for (int kc = 0; kc < 8; kc++)
            a[rt][kc] = *(const bf16x8*)(ab + (size_t)rt * 16 * 512 + kc * 64);

    const char* wsrc = (const char*)(Wqt + (size_t)e0 * NC);
#pragma unroll
    for (int ii = 0; ii < 2; ii++) {
        uint4 tmp[8];
#pragma unroll
        for (int j = 0; j < 8; j++) {
            int g = ((ii * 8 + j) * 256 + t) * 16;
            tmp[j] = *(const uint4*)(wsrc + g);
        }
#pragma unroll
        for (int j = 0; j < 8; j++) {
            int g = ((ii * 8 + j) * 256 + t) * 16;
            *(uint4*)(sB + (g ^ (((g >> 9) & 7) << 4))) = tmp[j];
        }
    }
    __syncthreads();

    f32x4 zero = {0.f, 0.f, 0.f, 0.f};
    f32x4 acc[2][8];
#pragma unroll
    for (int rt = 0; rt < 2; rt++)
#pragma unroll
        for (int et = 0; et < 8; et++) acc[rt][et] = zero;
    int swz = (l16 & 7) << 4;
#pragma unroll
    for (int kc = 0; kc < 8; kc++) {
        bf16x8 bB[8];
#pragma unroll
        for (int et = 0; et < 8; et++) {
            int e = et * 16 + l16;
            bB[et] = *(const bf16x8*)(sB + e * 512 + ((quad * 16 + kc * 64) ^ swz));
        }
#pragma unroll
        for (int et = 0; et < 8; et++) {
#pragma unroll
            for (int rt = 0; rt < 2; rt++)
                acc[rt][et] = __builtin_amdgcn_mfma_f32_16x16x32_bf16(a[rt][kc], bB[et], acc[rt][et], 0, 0, 0);
        }
    }
#pragma unroll
    for (int et = 0; et < 8; et++) {
        int e = e0 + et * 16 + l16;
        float bqv = bq[e];
#pragma unroll
        for (int rt = 0; rt < 2; rt++) {
#pragma unroll
            for (int rr = 0; rr < 4; rr++) {
                int s = r0 + rt * 16 + quad * 4 + rr;
                qbuf[((size_t)(b * NS + s)) * NE + e] = __float2bfloat16(acc[rt][et][rr] + bqv);
            }
        }
    }
}

// ---------------- K4: MFMA attention v5.
// 512-thread blocks, launch_bounds(512,2) (VGPR cap 256 -> NO forced spill;
// v4's (512,4) forced 64 VGPR and spilled P-state to scratch: FETCH 33->467MB).
// k-dim processed in TWO 128-wide halves: QK^T(8kt) -> exp/pack pk[16] ->
// PV(4kc), halving live regs (acc[8]+pk[16] vs acc[16]+pk[32]) so 4 waves/SIMD
// fit naturally. srow spans halves; normalize post-PV (exact).
__global__ void __launch_bounds__(512, 2) attn_kernel(const bf16* __restrict__ qbuf,
                                                      const bf16* __restrict__ kbuf,
                                                      const ushort* __restrict__ vtbuf,
                                                      const int* __restrict__ masks,
                                                      bf16* __restrict__ obuf) {
    int blk = blockIdx.x;          // bh*8 + chunk
    int chunk = blk & 7;
    int bh = blk >> 3;
    int h = bh & 3;
    int b = bh >> 2;
    int t = threadIdx.x;
    int w = t >> 6, lane = t & 63;  // w in 0..7
    int l16 = lane & 15, quad = lane >> 4;

    __shared__ __attribute__((aligned(16))) char sK[32768];  // [k=256][d-bytes=128] swz
    __shared__ __attribute__((aligned(16))) char sV[32768];  // [d=64][l-bytes=512] swz

    // ---- stage K and V^T (512 threads x 16B x 4 iters = 32KB each)
    const char* kgb = (const char*)kbuf + ((size_t)(b * NL) * NE + h * HDD) * 2;
    const char* vgb = (const char*)vtbuf + (size_t)bh * HDD * NL * 2;
#pragma unroll
    for (int i = 0; i < 4; i++) {
        int g = t * 16 + i * 8192;
        uint4 kv = *(const uint4*)(kgb + (size_t)(g >> 7) * 512 + (g & 127));
        *(uint4*)(sK + (g ^ (((g >> 7) & 7) << 4))) = kv;
        uint4 vv = *(const uint4*)(vgb + g);
        *(uint4*)(sV + (g ^ (((g >> 9) & 7) << 4))) = vv;
    }

    // ---- masks -> wave ballots -> per-lane nibble words (bit kt*4+r)
    const int* mp = masks + b * NL;
    unsigned long long bal0 = __ballot(mp[lane] != 0);
    unsigned long long bal1 = __ballot(mp[64 + lane] != 0);
    unsigned long long bal2 = __ballot(mp[128 + lane] != 0);
    unsigned long long bal3 = __ballot(mp[192 + lane] != 0);
    uint mw0 = 0, mw1 = 0;
#pragma unroll
    for (int kk = 0; kk < 4; kk++) {
        mw0 |= (uint)((bal0 >> (16 * kk + 4 * quad)) & 15ULL) << (4 * kk);
        mw0 |= (uint)((bal1 >> (16 * kk + 4 * quad)) & 15ULL) << (4 * kk + 16);
        mw1 |= (uint)((bal2 >> (16 * kk + 4 * quad)) & 15ULL) << (4 * kk);
        mw1 |= (uint)((bal3 >> (16 * kk + 4 * quad)) & 15ULL) << (4 * kk + 16);
    }

    __syncthreads();

    int sbase = chunk * 512;
    int kswz = (l16 & 7) << 4;
    int src0 = l16 + 32 * (quad & 1);
    int src1 = src0 + 16;
    bool ahi = quad >= 2;

    for (int it = 0; it < 4; it++) {
        int s0 = sbase + it * 128;
        const ushort* qp = (const ushort*)qbuf +
                           ((size_t)(b * NS + s0 + w * 16 + l16)) * NE + h * HDD + quad * 8;
        bf16x8 af0 = *(const bf16x8*)qp;
        bf16x8 af1 = *(const bf16x8*)(qp + 32);

        float srow = 0.f;
        f32x4 oacc[4];
#pragma unroll
        for (int dt = 0; dt < 4; dt++) oacc[dt] = f32x4{0.f, 0.f, 0.f, 0.f};

#pragma unroll
        for (int half = 0; half < 2; half++) {
            uint mw = half ? mw1 : mw0;
            int kbase = half * 128;  // k rows kbase..kbase+127

            // ---- QK^T (S^T) for this half: acc[kt][r] = S[q=l16][k=kbase+kt*16+quad*4+r]
            f32x4 acc[8];
#pragma unroll
            for (int kt = 0; kt < 8; kt++) {
                int row = kbase + kt * 16 + l16;
                bf16x8 kf0 = *(const bf16x8*)(sK + ((row * 128 + quad * 16) ^ kswz));
                bf16x8 kf1 = *(const bf16x8*)(sK + ((row * 128 + quad * 16 + 64) ^ kswz));
                f32x4 z = {0.f, 0.f, 0.f, 0.f};
                z = __builtin_amdgcn_mfma_f32_16x16x32_bf16(kf0, af0, z, 0, 0, 0);
                acc[kt] = __builtin_amdgcn_mfma_f32_16x16x32_bf16(kf1, af1, z, 0, 0, 0);
            }

            // ---- exp (hw) + mask + pack UNNORMALIZED bf16 pairs
            uint pk[16];
#pragma unroll
            for (int kt = 0; kt < 8; kt++) {
                uint nib = mw >> (4 * kt);
                float p0 = __expf(acc[kt][0] * 0.125f);
                float p1 = __expf(acc[kt][1] * 0.125f);
                float p2 = __expf(acc[kt][2] * 0.125f);
                float p3 = __expf(acc[kt][3] * 0.125f);
                p0 = (nib & 1) ? 0.f : p0;
                p1 = (nib & 2) ? 0.f : p1;
                p2 = (nib & 4) ? 0.f : p2;
                p3 = (nib & 8) ? 0.f : p3;
                srow += (p0 + p1) + (p2 + p3);
                pk[2 * kt] = (uint)us(p0) | ((uint)us(p1) << 16);
                pk[2 * kt + 1] = (uint)us(p2) | ((uint)us(p3) << 16);
            }

            // ---- PV for this half (kc covers k bytes (kbase + kc*32..)*2)
#pragma unroll
            for (int kc = 0; kc < 4; kc++) {
                uint a0 = (uint)__shfl((int)pk[4 * kc + 0], src0, 64);
                uint b0 = (uint)__shfl((int)pk[4 * kc + 2], src0, 64);
                uint a1 = (uint)__shfl((int)pk[4 * kc + 1], src0, 64);
                uint b1 = (uint)__shfl((int)pk[4 * kc + 3], src0, 64);
                uint a2 = (uint)__shfl((int)pk[4 * kc + 0], src1, 64);
                uint b2 = (uint)__shfl((int)pk[4 * kc + 2], src1, 64);
                uint a3 = (uint)__shfl((int)pk[4 * kc + 1], src1, 64);
                uint b3 = (uint)__shfl((int)pk[4 * kc + 3], src1, 64);
                union { uint u[4]; bf16x8 v; } pu;
                pu.u[0] = ahi ? b0 : a0;
                pu.u[1] = ahi ? b1 : a1;
                pu.u[2] = ahi ? b2 : a2;
                pu.u[3] = ahi ? b3 : a3;
                int kcg = half * 4 + kc;
#pragma unroll
                for (int dt = 0; dt < 4; dt++) {
                    int row = dt * 16 + l16;
                    bf16x8 vb = *(const bf16x8*)(sV + ((row * 512 + kcg * 64 + quad * 16) ^ kswz));
                    oacc[dt] = __builtin_amdgcn_mfma_f32_16x16x32_bf16(pu.v, vb, oacc[dt], 0, 0, 0);
                }
            }
        }

        srow += __shfl_xor(srow, 16, 64);
        srow += __shfl_xor(srow, 32, 64);
        float inv = 1.f / srow;
        float invr[4];
#pragma unroll
        for (int r = 0; r < 4; r++) invr[r] = __shfl(inv, quad * 4 + r, 64);

        // ---- normalize post-PV (rows q=quad*4+r) and store
        bf16* op = obuf + ((size_t)(b * NS + s0 + w * 16 + quad * 4)) * NE + h * HDD + l16;
#pragma unroll
        for (int dt = 0; dt < 4; dt++) {
#pragma unroll
            for (int r = 0; r < 4; r++)
                op[(size_t)r * NE + dt * 16] = __float2bfloat16(oacc[dt][r] * invr[r]);
        }
    }
}

// ---------------- K5: Y^T = Wo^T . o^T via MFMA -> AdaLN -> +x -> out [B,C,S].
__global__ void __launch_bounds__(256) out_kernel(const bf16* __restrict__ obuf,
                                                  const ushort* __restrict__ Wot,
                                                  const float* __restrict__ bo,
                                                  const float* __restrict__ mod,
                                                  const float* __restrict__ img_x,
                                                  float* __restrict__ out) {
    int blk = blockIdx.x;  // b * 64 + s-tile
    int b = blk >> 6;
    int s0 = (blk & 63) << 6;
    int t = threadIdx.x;
    int w = t >> 6, lane = t & 63, l16 = lane & 15, quad = lane >> 4;
    int c0 = w * 64;

    f32x4 zero = {0.f, 0.f, 0.f, 0.f};
    f32x4 acc[4][4];
#pragma unroll
    for (int ct = 0; ct < 4; ct++)
#pragma unroll
        for (int st = 0; st < 4; st++) acc[ct][st] = zero;

    const ushort* ap0 = Wot + (size_t)(c0 + l16) * NE + quad * 8;
    const ushort* bp0 = (const ushort*)obuf + ((size_t)(b * NS + s0 + l16)) * NE + quad * 8;
#pragma unroll
    for (int kc = 0; kc < 8; kc++) {
        bf16x8 a[4], bb[4];
#pragma unroll
        for (int ct = 0; ct < 4; ct++)
            a[ct] = *(const bf16x8*)(ap0 + (size_t)ct * 16 * NE + kc * 32);
#pragma unroll
        for (int st = 0; st < 4; st++)
            bb[st] = *(const bf16x8*)(bp0 + (size_t)st * 16 * NE + kc * 32);
#pragma unroll
        for (int ct = 0; ct < 4; ct++)
#pragma unroll
            for (int st = 0; st < 4; st++)
                acc[ct][st] = __builtin_amdgcn_mfma_f32_16x16x32_bf16(a[ct], bb[st], acc[ct][st], 0, 0, 0);
    }

#pragma unroll
    for (int ct = 0; ct < 4; ct++) {
#pragma unroll
        for (int r = 0; r < 4; r++) {
            int c = c0 + ct * 16 + quad * 4 + r;
            float sh = mod[b * 768 + c];
            float scv = mod[b * 768 + 256 + c];
            float ga = mod[b * 768 + 512 + c];
            float bov = bo[c];
            const float* xr = img_x + ((size_t)(b * NC + c)) * NS + s0;
            float* orow = out + ((size_t)(b * NC + c)) * NS + s0;
#pragma unroll
            for (int st = 0; st < 4; st++) {
                float y = ga * ((acc[ct][st][r] + bov) * (1.f + scv) + sh) + xr[st * 16 + l16];
                orow[st * 16 + l16] = y;
            }
        }
    }
}

extern "C" void kernel_launch(void* const* d_in, const int* in_sizes, int n_in,
                              void* d_out, int out_size, void* d_ws, size_t ws_size,
                              hipStream_t stream) {
    const float* img_x = (const float*)d_in[0];
    const float* refs = (const float*)d_in[1];
    const int* masks = (const int*)d_in[2];
    const float* ref_embeds = (const float*)d_in[3];
    const float* ln_img_w = (const float*)d_in[4];
    const float* ln_img_b = (const float*)d_in[5];
    const float* ln_txt_w = (const float*)d_in[6];
    const float* ln_txt_b = (const float*)d_in[7];
    const float* Wq = (const float*)d_in[8];
    const float* bq = (const float*)d_in[9];
    const float* Wk = (const float*)d_in[10];
    const float* bk = (const float*)d_in[11];
    const float* Wv = (const float*)d_in[12];
    const float* bv = (const float*)d_in[13];
    const float* Wo = (const float*)d_in[14];
    const float* bo = (const float*)d_in[15];
    const float* W_ada = (const float*)d_in[16];
    const float* b_ada = (const float*)d_in[17];
    float* out = (float*)d_out;

    char* ws = (char*)d_ws;
    float* mod = (float*)ws;                               // 49152 B
    ushort* wqt = (ushort*)(ws + 49152);                   // 128 KB
    ushort* wkt = (ushort*)(ws + 180224);                  // 128 KB
    ushort* wvt = (ushort*)(ws + 311296);                  // 128 KB
    ushort* wot = (ushort*)(ws + 442368);                  // 128 KB
    bf16* kbuf = (bf16*)(ws + 573440);                     // 2 MB
    ushort* vtbuf = (ushort*)(ws + 2670592);               // 2 MB
    bf16* qbuf = (bf16*)(ws + 4767744);                    // 33.5 MB
    bf16* obuf = (bf16*)(ws + 38322176);                   // 33.5 MB
    bf16* vbuf = obuf;     // alias: dead after vt_kernel
    ushort* xq = (ushort*)obuf;  // alias: written by xln (after vt), read by qmm,
                                 // dead once attn writes obuf

    hipLaunchKernelGGL(wt_kernel, dim3(32), dim3(256), 0, stream,
                       Wq, Wk, Wv, Wo, wqt, wkt, wvt, wot);
    hipLaunchKernelGGL(mod_kernel, dim3(NB * 12), dim3(256), 0, stream,
                       ref_embeds, W_ada, b_ada, mod);
    hipLaunchKernelGGL(kv_kernel, dim3(NB * 4), dim3(256), 0, stream,
                       refs, ln_txt_w, ln_txt_b, wkt, bk, wvt, bv, kbuf, vbuf);
    hipLaunchKernelGGL(vt_kernel, dim3(NB * NHH), dim3(256), 0, stream,
                       vbuf, vtbuf);
    hipLaunchKernelGGL(xln_kernel, dim3(NB * 16), dim3(256), 0, stream,
                       img_x, ln_img_w, ln_img_b, xq);
    hipLaunchKernelGGL(qmm_kernel, dim3(NB * 64), dim3(256), 0, stream,
                       xq, wqt, bq, qbuf);
    hipLaunchKernelGGL(attn_kernel, dim3(NB * NHH * 8), dim3(512), 0, stream,
                       qbuf, kbuf, vtbuf, masks, obuf);
    hipLaunchKernelGGL(out_kernel, dim3(NB * (NS / 64)), dim3(256), 0, stream,
                       obuf, wot, bo, mod, img_x, out);
}

// Round 11
// 364.990 us; speedup vs baseline: 1.5417x; 1.0401x over previous
//
#include <hip/hip_runtime.h>
#include <hip/hip_bf16.h>

#define NB 16
#define NC 256
#define NS 4096
#define NL 256
#define NE 256
#define NHH 4
#define HDD 64

using bf16 = __hip_bfloat16;
typedef short bf16x8 __attribute__((ext_vector_type(8)));
typedef float f32x4 __attribute__((ext_vector_type(4)));

__device__ __forceinline__ float bf16r(float x) {
    return __bfloat162float(__float2bfloat16(x));
}
__device__ __forceinline__ float rsqrt_nr(float x) {
    float r = rsqrtf(x);
    r = r * (1.5f - 0.5f * x * r * r);
    return r;
}
__device__ __forceinline__ ushort us(float x) {
    bf16 h = __float2bfloat16(x);
    return *(ushort*)&h;
}

// ---------------- K0: merged weight-transpose (blk<32) + AdaLN mod (blk>=32).
// wt: W [in][out] fp32 -> Wt bf16 [out][in]. mod: silu(ref_embeds)@W_ada+b_ada.
__global__ void __launch_bounds__(256) wtmod_kernel(const float* __restrict__ Wq,
                                                    const float* __restrict__ Wk,
                                                    const float* __restrict__ Wv,
                                                    const float* __restrict__ Wo,
                                                    ushort* __restrict__ wqt,
                                                    ushort* __restrict__ wkt,
                                                    ushort* __restrict__ wvt,
                                                    ushort* __restrict__ wot,
                                                    const float* __restrict__ ref_embeds,
                                                    const float* __restrict__ W_ada,
                                                    const float* __restrict__ b_ada,
                                                    float* __restrict__ mod) {
    __shared__ float tile[32 * 257];
    __shared__ float silu[NC];
    __shared__ float part[256];
    int t = threadIdx.x;
    if (blockIdx.x < 32) {
        int m = blockIdx.x >> 3, strip = blockIdx.x & 7;
        const float* W = (m == 0) ? Wq : (m == 1) ? Wk : (m == 2) ? Wv : Wo;
        ushort* Wt = (m == 0) ? wqt : (m == 1) ? wkt : (m == 2) ? wvt : wot;
        int in0 = strip * 32;
        for (int i = 0; i < 32; i++) tile[i * 257 + t] = W[(size_t)(in0 + i) * 256 + t];
        __syncthreads();
        ushort vals[32];
#pragma unroll
        for (int i = 0; i < 32; i++) vals[i] = us(tile[i * 257 + t]);
#pragma unroll
        for (int i = 0; i < 32; i += 8)
            *(uint4*)(Wt + (size_t)t * 256 + in0 + i) = *(const uint4*)(vals + i);
    } else {
        int blk = blockIdx.x - 32;
        int b = blk / 12, jc = blk % 12;
        float x = ref_embeds[b * NC + t];
        silu[t] = x / (1.f + expf(-x));
        __syncthreads();
        int j = jc * 64 + (t & 63);
        int cq = t >> 6;
        float acc = 0.f;
#pragma unroll 8
        for (int c = cq * 64; c < cq * 64 + 64; c++) acc += silu[c] * W_ada[c * 3 * NC + j];
        part[t] = acc;
        __syncthreads();
        if (t < 64) {
            mod[b * 3 * NC + j] = part[t] + part[t + 64] + part[t + 128] + part[t + 192] + b_ada[j];
        }
    }
}

// ---------------- K2: LN(refs) -> K,V projections via MFMA; V written
// TRANSPOSED directly to vtbuf via an LDS bounce (vt_kernel folded in).
__global__ void __launch_bounds__(256) kv_kernel(const float* __restrict__ refs,
                                                 const float* __restrict__ lw,
                                                 const float* __restrict__ lb,
                                                 const ushort* __restrict__ Wkt,
                                                 const float* __restrict__ bk,
                                                 const ushort* __restrict__ Wvt,
                                                 const float* __restrict__ bv,
                                                 bf16* __restrict__ kbuf,
                                                 ushort* __restrict__ vtbuf) {
    int blk = blockIdx.x;  // b*4 + lgroup
    int b = blk >> 2;
    int l0 = (blk & 3) << 6;
    int t = threadIdx.x;
    __shared__ ushort At[64 * 264];  // 16896 ushorts; later reused as [256][66]
    __shared__ float lws[NC], lbs[NC];
    lws[t] = lw[t];
    lbs[t] = lb[t];
    int r = t >> 2, j = t & 3;
    const float* rp = refs + ((size_t)(b * NL + l0 + r)) * NC + j * 64;
    float v[64];
#pragma unroll
    for (int i = 0; i < 16; i++) {
        float4 f = *(const float4*)(rp + i * 4);
        v[i * 4 + 0] = f.x; v[i * 4 + 1] = f.y; v[i * 4 + 2] = f.z; v[i * 4 + 3] = f.w;
    }
    float s = 0;
#pragma unroll
    for (int i = 0; i < 64; i++) s += v[i];
    s += __shfl_xor(s, 1, 64);
    s += __shfl_xor(s, 2, 64);
    float mu = s * (1.f / NC);
    float vr = 0;
#pragma unroll
    for (int i = 0; i < 64; i++) {
        float d = v[i] - mu;
        vr += d * d;
    }
    vr += __shfl_xor(vr, 1, 64);
    vr += __shfl_xor(vr, 2, 64);
    float rs = rsqrt_nr(vr * (1.f / NC) + 1e-5f);
    __syncthreads();  // lws/lbs ready
    ushort nv[64];
#pragma unroll
    for (int i = 0; i < 64; i++) {
        int c = j * 64 + i;
        nv[i] = us((v[i] - mu) * rs * lws[c] + lbs[c]);
    }
#pragma unroll
    for (int i = 0; i < 64; i += 4)
        *(uint2*)(At + r * 264 + j * 64 + i) = *(const uint2*)(nv + i);
    __syncthreads();

    int w = t >> 6, lane = t & 63, l16 = lane & 15, quad = lane >> 4;
    int r0 = w * 16;
    f32x4 zero = {0.f, 0.f, 0.f, 0.f};
    f32x4 ak[16], av[16];
#pragma unroll
    for (int et = 0; et < 16; et++) { ak[et] = zero; av[et] = zero; }
    const ushort* ap = At + (r0 + l16) * 264 + quad * 8;
    const ushort* kp = Wkt + (size_t)l16 * NC + quad * 8;
    const ushort* vp = Wvt + (size_t)l16 * NC + quad * 8;
#pragma unroll
    for (int kc = 0; kc < 8; kc++) {
        bf16x8 a = *(const bf16x8*)(ap + kc * 32);
#pragma unroll
        for (int et = 0; et < 16; et++) {
            bf16x8 bbk = *(const bf16x8*)(kp + (size_t)et * 16 * NC + kc * 32);
            ak[et] = __builtin_amdgcn_mfma_f32_16x16x32_bf16(a, bbk, ak[et], 0, 0, 0);
        }
#pragma unroll
        for (int et = 0; et < 16; et++) {
            bf16x8 bbv = *(const bf16x8*)(vp + (size_t)et * 16 * NC + kc * 32);
            av[et] = __builtin_amdgcn_mfma_f32_16x16x32_bf16(a, bbv, av[et], 0, 0, 0);
        }
    }
    // K: direct store (row-major [B,L,E])
#pragma unroll
    for (int et = 0; et < 16; et++) {
        int e = et * 16 + l16;
        float bkv = bk[e];
#pragma unroll
        for (int rr = 0; rr < 4; rr++) {
            size_t row = (size_t)(b * NL + l0 + r0 + quad * 4 + rr);
            kbuf[row * NE + e] = __float2bfloat16(ak[et][rr] + bkv);
        }
    }
    // V: transpose via LDS bounce (At reused as [256 e][66]), write vtbuf
    __syncthreads();  // all At MFMA reads done
    ushort* vtt = At;
#pragma unroll
    for (int et = 0; et < 16; et++) {
        int e = et * 16 + l16;
        float bvv = bv[e];
#pragma unroll
        for (int rr = 0; rr < 4; rr++)
            vtt[e * 66 + r0 + quad * 4 + rr] = us(av[et][rr] + bvv);
    }
    __syncthreads();
#pragma unroll
    for (int i = 0; i < 8; i++) {
        int e = i * 32 + (t >> 3);
        int ll = (t & 7) * 8;
        const ushort* tp = vtt + e * 66 + ll;
        uint u0 = *(const uint*)(tp);
        uint u1 = *(const uint*)(tp + 2);
        uint u2 = *(const uint*)(tp + 4);
        uint u3 = *(const uint*)(tp + 6);
        uint4 uu = {u0, u1, u2, u3};
        *(uint4*)(vtbuf + ((size_t)(b * 256 + e)) * NL + l0 + ll) = uu;
    }
}

// ---------------- K3a: transpose + LN: img_x [B,C,S] fp32 -> xq [B,S,C] bf16.
__global__ void __launch_bounds__(256) xln_kernel(const float* __restrict__ img_x,
                                                  const float* __restrict__ lw,
                                                  const float* __restrict__ lb,
                                                  ushort* __restrict__ xq) {
    int blk = blockIdx.x;  // b*16 + schunk
    int b = blk >> 4;
    int sb = (blk & 15) << 8;
    int t = threadIdx.x;
    int l63 = t & 63, wq = t >> 6;
    __shared__ float part_s[4][256], part_q[4][256];
    __shared__ float mu_s[256], rs_s[256];
    __shared__ ushort tile[256 * 66];
    __shared__ float lws[NC], lbs[NC];
    lws[t] = lw[t];
    lbs[t] = lb[t];

    const float* xb = img_x + (size_t)b * NC * NS + sb;
    float s0 = 0.f, s1 = 0.f, s2 = 0.f, s3 = 0.f;
    float q0 = 0.f, q1 = 0.f, q2 = 0.f, q3 = 0.f;
    for (int it = 0; it < 64; it++) {
        int c = it * 4 + wq;
        float4 v = *(const float4*)(xb + (size_t)c * NS + l63 * 4);
        s0 += v.x; q0 += v.x * v.x;
        s1 += v.y; q1 += v.y * v.y;
        s2 += v.z; q2 += v.z * v.z;
        s3 += v.w; q3 += v.w * v.w;
    }
    part_s[wq][l63 * 4 + 0] = s0; part_q[wq][l63 * 4 + 0] = q0;
    part_s[wq][l63 * 4 + 1] = s1; part_q[wq][l63 * 4 + 1] = q1;
    part_s[wq][l63 * 4 + 2] = s2; part_q[wq][l63 * 4 + 2] = q2;
    part_s[wq][l63 * 4 + 3] = s3; part_q[wq][l63 * 4 + 3] = q3;
    __syncthreads();
    {
        float sm = part_s[0][t] + part_s[1][t] + part_s[2][t] + part_s[3][t];
        float sq = part_q[0][t] + part_q[1][t] + part_q[2][t] + part_q[3][t];
        float mu = sm * (1.f / NC);
        mu_s[t] = mu;
        rs_s[t] = rsqrt_nr(sq * (1.f / NC) - mu * mu + 1e-5f);
    }
    __syncthreads();
    float4 mu4 = *(const float4*)&mu_s[l63 * 4];
    float4 rs4 = *(const float4*)&rs_s[l63 * 4];
    for (int ch = 0; ch < 4; ch++) {
#pragma unroll
        for (int it2 = 0; it2 < 16; it2++) {
            int cl = it2 * 4 + wq;
            int c = ch * 64 + cl;
            float4 v = *(const float4*)(xb + (size_t)c * NS + l63 * 4);
            float wv = lws[c], bb = lbs[c];
            tile[(l63 * 4 + 0) * 66 + cl] = us((v.x - mu4.x) * rs4.x * wv + bb);
            tile[(l63 * 4 + 1) * 66 + cl] = us((v.y - mu4.y) * rs4.y * wv + bb);
            tile[(l63 * 4 + 2) * 66 + cl] = us((v.z - mu4.z) * rs4.z * wv + bb);
            tile[(l63 * 4 + 3) * 66 + cl] = us((v.w - mu4.w) * rs4.w * wv + bb);
        }
        __syncthreads();
        ushort* xrow = xq + ((size_t)(b * NS + sb)) * NC + ch * 64 + (t & 7) * 8;
#pragma unroll
        for (int i = 0; i < 8; i++) {
            int s = i * 32 + (t >> 3);
            const ushort* tp = tile + s * 66 + (t & 7) * 8;
            uint u0 = *(const uint*)(tp);
            uint u1 = *(const uint*)(tp + 2);
            uint u2 = *(const uint*)(tp + 4);
            uint u3 = *(const uint*)(tp + 6);
            uint4 uu = {u0, u1, u2, u3};
            *(uint4*)(xrow + (size_t)s * NC) = uu;
        }
        __syncthreads();
    }
}

// ---------------- K3b: Q GEMM: qbuf = xq @ Wqt^T + bq (unchanged).
__global__ void __launch_bounds__(256, 2) qmm_kernel(const ushort* __restrict__ xq,
                                                     const ushort* __restrict__ Wqt,
                                                     const float* __restrict__ bq,
                                                     bf16* __restrict__ qbuf) {
    int blk = blockIdx.x;  // b*64 + rc*2 + eh
    int b = blk >> 6;
    int rc = (blk >> 1) & 31;
    int eh = blk & 1;
    int t = threadIdx.x;
    int w = t >> 6, lane = t & 63, l16 = lane & 15, quad = lane >> 4;
    int r0 = rc * 128 + w * 32;
    int e0 = eh * 128;

    __shared__ __attribute__((aligned(16))) char sB[65536];

    const char* ab = (const char*)xq + ((size_t)(b * NS + r0 + l16)) * 512 + quad * 16;
    bf16x8 a[2][8];
#pragma unroll
    for (int rt = 0; rt < 2; rt++)
#pragma unroll
        for (int kc = 0; kc < 8; kc++)
            a[rt][kc] = *(const bf16x8*)(ab + (size_t)rt * 16 * 512 + kc * 64);

    const char* wsrc = (const char*)(Wqt + (size_t)e0 * NC);
#pragma unroll
    for (int ii = 0; ii < 2; ii++) {
        uint4 tmp[8];
#pragma unroll
        for (int j = 0; j < 8; j++) {
            int g = ((ii * 8 + j) * 256 + t) * 16;
            tmp[j] = *(const uint4*)(wsrc + g);
        }
#pragma unroll
        for (int j = 0; j < 8; j++) {
            int g = ((ii * 8 + j) * 256 + t) * 16;
            *(uint4*)(sB + (g ^ (((g >> 9) & 7) << 4))) = tmp[j];
        }
    }
    __syncthreads();

    f32x4 zero = {0.f, 0.f, 0.f, 0.f};
    f32x4 acc[2][8];
#pragma unroll
    for (int rt = 0; rt < 2; rt++)
#pragma unroll
        for (int et = 0; et < 8; et++) acc[rt][et] = zero;
    int swz = (l16 & 7) << 4;
#pragma unroll
    for (int kc = 0; kc < 8; kc++) {
        bf16x8 bB[8];
#pragma unroll
        for (int et = 0; et < 8; et++) {
            int e = et * 16 + l16;
            bB[et] = *(const bf16x8*)(sB + e * 512 + ((quad * 16 + kc * 64) ^ swz));
        }
#pragma unroll
        for (int et = 0; et < 8; et++) {
#pragma unroll
            for (int rt = 0; rt < 2; rt++)
                acc[rt][et] = __builtin_amdgcn_mfma_f32_16x16x32_bf16(a[rt][kc], bB[et], acc[rt][et], 0, 0, 0);
        }
    }
#pragma unroll
    for (int et = 0; et < 8; et++) {
        int e = e0 + et * 16 + l16;
        float bqv = bq[e];
#pragma unroll
        for (int rt = 0; rt < 2; rt++) {
#pragma unroll
            for (int rr = 0; rr < 4; rr++) {
                int s = r0 + rt * 16 + quad * 4 + rr;
                qbuf[((size_t)(b * NS + s)) * NE + e] = __float2bfloat16(acc[rt][et][rr] + bqv);
            }
        }
    }
}

// ---------------- K4: MFMA attention (R8-exact: best measured, 79.5us, no spill).
__global__ void __launch_bounds__(256) attn_kernel(const bf16* __restrict__ qbuf,
                                                   const bf16* __restrict__ kbuf,
                                                   const ushort* __restrict__ vtbuf,
                                                   const int* __restrict__ masks,
                                                   bf16* __restrict__ obuf) {
    int blk = blockIdx.x;          // bh*8 + chunk
    int chunk = blk & 7;
    int bh = blk >> 3;
    int h = bh & 3;
    int b = bh >> 2;
    int t = threadIdx.x;
    int w = t >> 6, lane = t & 63;
    int l16 = lane & 15, quad = lane >> 4;

    __shared__ __attribute__((aligned(16))) char sK[32768];  // [k=256][d-bytes=128] swz
    __shared__ __attribute__((aligned(16))) char sV[32768];  // [d=64][l-bytes=512] swz

    const char* kgb = (const char*)kbuf + ((size_t)(b * NL) * NE + h * HDD) * 2;
    const char* vgb = (const char*)vtbuf + (size_t)bh * HDD * NL * 2;
#pragma unroll
    for (int i = 0; i < 8; i++) {
        int g = t * 16 + i * 4096;
        uint4 kv = *(const uint4*)(kgb + (size_t)(g >> 7) * 512 + (g & 127));
        *(uint4*)(sK + (g ^ (((g >> 7) & 7) << 4))) = kv;
        uint4 vv = *(const uint4*)(vgb + g);
        *(uint4*)(sV + (g ^ (((g >> 9) & 7) << 4))) = vv;
    }

    const int* mp = masks + b * NL;
    unsigned long long bal0 = __ballot(mp[lane] != 0);
    unsigned long long bal1 = __ballot(mp[64 + lane] != 0);
    unsigned long long bal2 = __ballot(mp[128 + lane] != 0);
    unsigned long long bal3 = __ballot(mp[192 + lane] != 0);
    uint mw0 = 0, mw1 = 0;
#pragma unroll
    for (int kk = 0; kk < 4; kk++) {
        mw0 |= (uint)((bal0 >> (16 * kk + 4 * quad)) & 15ULL) << (4 * kk);
        mw0 |= (uint)((bal1 >> (16 * kk + 4 * quad)) & 15ULL) << (4 * kk + 16);
        mw1 |= (uint)((bal2 >> (16 * kk + 4 * quad)) & 15ULL) << (4 * kk);
        mw1 |= (uint)((bal3 >> (16 * kk + 4 * quad)) & 15ULL) << (4 * kk + 16);
    }

    int sbase = chunk * 512;
    const ushort* qp0 = (const ushort*)qbuf +
                        ((size_t)(b * NS + sbase + w * 16 + l16)) * NE + h * HDD + quad * 8;
    bf16x8 af0 = *(const bf16x8*)qp0;
    bf16x8 af1 = *(const bf16x8*)(qp0 + 32);

    __syncthreads();

    int kswz = (l16 & 7) << 4;
    int src0 = l16 + 32 * (quad & 1);
    int src1 = src0 + 16;
    bool ahi = quad >= 2;

    for (int it = 0; it < 8; it++) {
        int s0 = sbase + it * 64;
        bf16x8 nf0, nf1;
        if (it < 7) {
            const ushort* qn = qp0 + (size_t)(it + 1) * 64 * NE;
            nf0 = *(const bf16x8*)qn;
            nf1 = *(const bf16x8*)(qn + 32);
        }

        f32x4 acc[16];
#pragma unroll
        for (int kt = 0; kt < 16; kt++) {
            int row = kt * 16 + l16;
            bf16x8 kf0 = *(const bf16x8*)(sK + ((row * 128 + quad * 16) ^ kswz));
            bf16x8 kf1 = *(const bf16x8*)(sK + ((row * 128 + quad * 16 + 64) ^ kswz));
            f32x4 z = {0.f, 0.f, 0.f, 0.f};
            z = __builtin_amdgcn_mfma_f32_16x16x32_bf16(kf0, af0, z, 0, 0, 0);
            acc[kt] = __builtin_amdgcn_mfma_f32_16x16x32_bf16(kf1, af1, z, 0, 0, 0);
        }

        float srow = 0.f;
#pragma unroll
        for (int kt = 0; kt < 16; kt++) {
            uint nib = ((kt < 8) ? mw0 : mw1) >> (4 * (kt & 7));
#pragma unroll
            for (int r = 0; r < 4; r++) {
                float p = exp2f(bf16r(acc[kt][r]) * 0.18033688f);  // 0.125*log2(e)
                p = ((nib >> r) & 1) ? 0.f : p;
                acc[kt][r] = p;
                srow += p;
            }
        }
        srow += __shfl_xor(srow, 16, 64);
        srow += __shfl_xor(srow, 32, 64);
        float inv = 1.f / srow;

        uint Wloc[32];
#pragma unroll
        for (int kt = 0; kt < 16; kt++) {
            Wloc[2 * kt] = (uint)us(acc[kt][0] * inv) | ((uint)us(acc[kt][1] * inv) << 16);
            Wloc[2 * kt + 1] = (uint)us(acc[kt][2] * inv) | ((uint)us(acc[kt][3] * inv) << 16);
        }

        f32x4 oacc[4];
#pragma unroll
        for (int dt = 0; dt < 4; dt++) oacc[dt] = f32x4{0.f, 0.f, 0.f, 0.f};
#pragma unroll
        for (int kc = 0; kc < 8; kc++) {
            uint a0 = (uint)__shfl((int)Wloc[4 * kc + 0], src0, 64);
            uint b0 = (uint)__shfl((int)Wloc[4 * kc + 2], src0, 64);
            uint a1 = (uint)__shfl((int)Wloc[4 * kc + 1], src0, 64);
            uint b1 = (uint)__shfl((int)Wloc[4 * kc + 3], src0, 64);
            uint a2 = (uint)__shfl((int)Wloc[4 * kc + 0], src1, 64);
            uint b2 = (uint)__shfl((int)Wloc[4 * kc + 2], src1, 64);
            uint a3 = (uint)__shfl((int)Wloc[4 * kc + 1], src1, 64);
            uint b3 = (uint)__shfl((int)Wloc[4 * kc + 3], src1, 64);
            union { uint u[4]; bf16x8 v; } pu;
            pu.u[0] = ahi ? b0 : a0;
            pu.u[1] = ahi ? b1 : a1;
            pu.u[2] = ahi ? b2 : a2;
            pu.u[3] = ahi ? b3 : a3;
#pragma unroll
            for (int dt = 0; dt < 4; dt++) {
                int row = dt * 16 + l16;
                bf16x8 vb = *(const bf16x8*)(sV + ((row * 512 + kc * 64 + quad * 16) ^ kswz));
                oacc[dt] = __builtin_amdgcn_mfma_f32_16x16x32_bf16(pu.v, vb, oacc[dt], 0, 0, 0);
            }
        }

        bf16* op = obuf + ((size_t)(b * NS + s0 + w * 16 + quad * 4)) * NE + h * HDD + l16;
#pragma unroll
        for (int dt = 0; dt < 4; dt++) {
#pragma unroll
            for (int r = 0; r < 4; r++)
                op[(size_t)r * NE + dt * 16] = __float2bfloat16(oacc[dt][r]);
        }
        if (it < 7) { af0 = nf0; af1 = nf1; }
    }
}

// ---------------- K5: Y^T = Wo^T . o^T via MFMA -> AdaLN -> +x -> out [B,C,S].
__global__ void __launch_bounds__(256) out_kernel(const bf16* __restrict__ obuf,
                                                  const ushort* __restrict__ Wot,
                                                  const float* __restrict__ bo,
                                                  const float* __restrict__ mod,
                                                  const float* __restrict__ img_x,
                                                  float* __restrict__ out) {
    int blk = blockIdx.x;  // b * 64 + s-tile
    int b = blk >> 6;
    int s0 = (blk & 63) << 6;
    int t = threadIdx.x;
    int w = t >> 6, lane = t & 63, l16 = lane & 15, quad = lane >> 4;
    int c0 = w * 64;

    f32x4 zero = {0.f, 0.f, 0.f, 0.f};
    f32x4 acc[4][4];
#pragma unroll
    for (int ct = 0; ct < 4; ct++)
#pragma unroll
        for (int st = 0; st < 4; st++) acc[ct][st] = zero;

    const ushort* ap0 = Wot + (size_t)(c0 + l16) * NE + quad * 8;
    const ushort* bp0 = (const ushort*)obuf + ((size_t)(b * NS + s0 + l16)) * NE + quad * 8;
#pragma unroll
    for (int kc = 0; kc < 8; kc++) {
        bf16x8 a[4], bb[4];
#pragma unroll
        for (int ct = 0; ct < 4; ct++)
            a[ct] = *(const bf16x8*)(ap0 + (size_t)ct * 16 * NE + kc * 32);
#pragma unroll
        for (int st = 0; st < 4; st++)
            bb[st] = *(const bf16x8*)(bp0 + (size_t)st * 16 * NE + kc * 32);
#pragma unroll
        for (int ct = 0; ct < 4; ct++)
#pragma unroll
            for (int st = 0; st < 4; st++)
                acc[ct][st] = __builtin_amdgcn_mfma_f32_16x16x32_bf16(a[ct], bb[st], acc[ct][st], 0, 0, 0);
    }

#pragma unroll
    for (int ct = 0; ct < 4; ct++) {
#pragma unroll
        for (int r = 0; r < 4; r++) {
            int c = c0 + ct * 16 + quad * 4 + r;
            float sh = mod[b * 768 + c];
            float scv = mod[b * 768 + 256 + c];
            float ga = mod[b * 768 + 512 + c];
            float bov = bo[c];
            const float* xr = img_x + ((size_t)(b * NC + c)) * NS + s0;
            float* orow = out + ((size_t)(b * NC + c)) * NS + s0;
#pragma unroll
            for (int st = 0; st < 4; st++) {
                float y = ga * ((acc[ct][st][r] + bov) * (1.f + scv) + sh) + xr[st * 16 + l16];
                orow[st * 16 + l16] = y;
            }
        }
    }
}

extern "C" void kernel_launch(void* const* d_in, const int* in_sizes, int n_in,
                              void* d_out, int out_size, void* d_ws, size_t ws_size,
                              hipStream_t stream) {
    const float* img_x = (const float*)d_in[0];
    const float* refs = (const float*)d_in[1];
    const int* masks = (const int*)d_in[2];
    const float* ref_embeds = (const float*)d_in[3];
    const float* ln_img_w = (const float*)d_in[4];
    const float* ln_img_b = (const float*)d_in[5];
    const float* ln_txt_w = (const float*)d_in[6];
    const float* ln_txt_b = (const float*)d_in[7];
    const float* Wq = (const float*)d_in[8];
    const float* bq = (const float*)d_in[9];
    const float* Wk = (const float*)d_in[10];
    const float* bk = (const float*)d_in[11];
    const float* Wv = (const float*)d_in[12];
    const float* bv = (const float*)d_in[13];
    const float* Wo = (const float*)d_in[14];
    const float* bo = (const float*)d_in[15];
    const float* W_ada = (const float*)d_in[16];
    const float* b_ada = (const float*)d_in[17];
    float* out = (float*)d_out;

    char* ws = (char*)d_ws;
    float* mod = (float*)ws;                               // 49152 B
    ushort* wqt = (ushort*)(ws + 49152);                   // 128 KB
    ushort* wkt = (ushort*)(ws + 180224);                  // 128 KB
    ushort* wvt = (ushort*)(ws + 311296);                  // 128 KB
    ushort* wot = (ushort*)(ws + 442368);                  // 128 KB
    bf16* kbuf = (bf16*)(ws + 573440);                     // 2 MB
    ushort* vtbuf = (ushort*)(ws + 2670592);               // 2 MB
    bf16* qbuf = (bf16*)(ws + 4767744);                    // 33.5 MB
    bf16* obuf = (bf16*)(ws + 38322176);                   // 33.5 MB
    ushort* xq = (ushort*)obuf;  // alias: written by xln, read by qmm,
                                 // dead once attn writes obuf

    hipLaunchKernelGGL(wtmod_kernel, dim3(32 + NB * 12), dim3(256), 0, stream,
                       Wq, Wk, Wv, Wo, wqt, wkt, wvt, wot,
                       ref_embeds, W_ada, b_ada, mod);
    hipLaunchKernelGGL(kv_kernel, dim3(NB * 4), dim3(256), 0, stream,
                       refs, ln_txt_w, ln_txt_b, wkt, bk, wvt, bv, kbuf, vtbuf);
    hipLaunchKernelGGL(xln_kernel, dim3(NB * 16), dim3(256), 0, stream,
                       img_x, ln_img_w, ln_img_b, xq);
    hipLaunchKernelGGL(qmm_kernel, dim3(NB * 64), dim3(256), 0, stream,
                       xq, wqt, bq, qbuf);
    hipLaunchKernelGGL(attn_kernel, dim3(NB * NHH * 8), dim3(256), 0, stream,
                       qbuf, kbuf, vtbuf, masks, obuf);
    hipLaunchKernelGGL(out_kernel, dim3(NB * (NS / 64)), dim3(256), 0, stream,
                       obuf, wot, bo, mod, img_x, out);
}